// Round 2
// baseline (688.628 us; speedup 1.0000x reference)
//
#include <hip/hip_runtime.h>
#include <hip/hip_bf16.h>
#include <stdint.h>

#define N_TOK 4096
#define CDIM 2048
#define EXP 8
#define FDIM 1024

typedef __attribute__((ext_vector_type(4))) float f32x4;
typedef __attribute__((ext_vector_type(8))) short bf16x8;

// async global->LDS, 16B per lane; LDS dest = wave-uniform base + lane*16 (m104/m108)
__device__ __forceinline__ void g2l16(const void* g, void* l) {
  __builtin_amdgcn_global_load_lds(
      (const __attribute__((address_space(1))) void*)g,
      (__attribute__((address_space(3))) void*)l, 16, 0, 0);
}

// ---------------- transpose + fp32->bf16: in [E][R][Cc] -> out [E][Cc][R] ----------------
// 64 in-rows x 32 in-cols per block; float4 reads, int4 (8x bf16) writes.
__global__ __launch_bounds__(256) void transpose_to_bf16(
    const float* __restrict__ in, __hip_bfloat16* __restrict__ out, int R, int Cc) {
  __shared__ float tile[32][65];
  int e = blockIdx.z;
  const float* ip = in + (size_t)e * R * Cc;
  __hip_bfloat16* op = out + (size_t)e * R * Cc;
  int r0 = blockIdx.y * 64, c0 = blockIdx.x * 32;
  int t = threadIdx.x;
#pragma unroll
  for (int p = 0; p < 2; p++) {
    int f = t + p * 256;
    int r = f >> 3, c4 = (f & 7) * 4;
    float4 v = *(const float4*)(ip + (size_t)(r0 + r) * Cc + c0 + c4);
    tile[c4 + 0][r] = v.x;
    tile[c4 + 1][r] = v.y;
    tile[c4 + 2][r] = v.z;
    tile[c4 + 3][r] = v.w;
  }
  __syncthreads();
  int c = t >> 3, seg = (t & 7) * 8;
  union { int4 v; __hip_bfloat16 h[8]; } u;
#pragma unroll
  for (int j = 0; j < 8; j++) u.h[j] = __float2bfloat16(tile[c][seg + j]);
  *(int4*)(op + (size_t)(c0 + c) * R + r0 + seg) = u.v;
}

// ---------------- fp32 router + x->bf16 ----------------
__global__ __launch_bounds__(256) void router_kernel(
    const float* __restrict__ x, const float* __restrict__ wr,
    __hip_bfloat16* __restrict__ x_bf, int* __restrict__ counts,
    int* __restrict__ pair_expert, float* __restrict__ pair_prob) {
  int tok = blockIdx.x;
  const float* xr = x + (size_t)tok * CDIM;
  int t = threadIdx.x;
  float acc[EXP];
#pragma unroll
  for (int e = 0; e < EXP; e++) acc[e] = 0.f;
#pragma unroll
  for (int j = 0; j < 8; j++) {
    int c = j * 256 + t;
    float xv = xr[c];
    x_bf[(size_t)tok * CDIM + c] = __float2bfloat16(xv);
    const float4* wr4 = (const float4*)(wr + (size_t)c * EXP);
    float4 wa = wr4[0], wb = wr4[1];
    acc[0] += xv * wa.x; acc[1] += xv * wa.y; acc[2] += xv * wa.z; acc[3] += xv * wa.w;
    acc[4] += xv * wb.x; acc[5] += xv * wb.y; acc[6] += xv * wb.z; acc[7] += xv * wb.w;
  }
#pragma unroll
  for (int e = 0; e < EXP; e++) {
#pragma unroll
    for (int off = 32; off > 0; off >>= 1) acc[e] += __shfl_down(acc[e], off, 64);
  }
  __shared__ float wsum[4][EXP];
  int wid = t >> 6, lane = t & 63;
  if (lane == 0) {
#pragma unroll
    for (int e = 0; e < EXP; e++) wsum[wid][e] = acc[e];
  }
  __syncthreads();
  if (t == 0) {
    float lg[EXP];
#pragma unroll
    for (int e = 0; e < EXP; e++) lg[e] = wsum[0][e] + wsum[1][e] + wsum[2][e] + wsum[3][e];
    int i0 = 0;
#pragma unroll
    for (int e = 1; e < EXP; e++) if (lg[e] > lg[i0]) i0 = e;
    int i1 = (i0 == 0) ? 1 : 0;
#pragma unroll
    for (int e = 0; e < EXP; e++) if (e != i0 && lg[e] > lg[i1]) i1 = e;
    float e1 = __expf(lg[i1] - lg[i0]);
    float p0 = 1.f / (1.f + e1);
    pair_expert[tok * 2 + 0] = i0;
    pair_expert[tok * 2 + 1] = i1;
    pair_prob[tok * 2 + 0] = p0;
    pair_prob[tok * 2 + 1] = e1 * p0;
    atomicAdd(&counts[i0], 1);
    atomicAdd(&counts[i1], 1);
  }
}

// ---------------- tiny exclusive scan over 8 counts ----------------
__global__ void scan_kernel(const int* __restrict__ counts, int* __restrict__ bases) {
  if (threadIdx.x == 0) {
    int s = 0;
    for (int e = 0; e < EXP; e++) { bases[e] = s; s += counts[e]; }
  }
}

// ---------------- scatter pairs into per-expert lists ----------------
__global__ __launch_bounds__(256) void scatter_kernel(
    const int* __restrict__ pair_expert, const int* __restrict__ bases,
    int* __restrict__ cursors, int* __restrict__ lists) {
  int tok = blockIdx.x * 256 + threadIdx.x;
  if (tok >= N_TOK) return;
#pragma unroll
  for (int k = 0; k < 2; k++) {
    int e = pair_expert[tok * 2 + k];
    int pos = atomicAdd(&cursors[e], 1);
    lists[bases[e] + pos] = tok * 2 + k;
  }
}

// ---------------- GEMM1: h = silu(x@w1) * (x@w3), gathered rows, fused gate/up ----------------
// LDS is fragment-order sub-tiles (16 rows x 32 k = 1024B, chunk L = [row L&15][k (L>>4)*8..+8])
// so global_load_lds's lane*16 write pattern IS the MFMA fragment layout; ds_read = base+lane*16.
__global__ __launch_bounds__(256) void gemm1_kernel(
    const __hip_bfloat16* __restrict__ xbf, const __hip_bfloat16* __restrict__ w1t,
    const __hip_bfloat16* __restrict__ w3t, const int* __restrict__ counts,
    const int* __restrict__ bases, const int* __restrict__ lists,
    __hip_bfloat16* __restrict__ h) {
  int e = blockIdx.z;
  int n_e = counts[e];
  int m0 = blockIdx.y * 128;
  if (m0 >= n_e) return;
  int base = bases[e];
  int f0 = blockIdx.x * 64;

  __shared__ alignas(16) short As[128 * 32];   // 8 sub-tiles
  __shared__ alignas(16) short B1s[64 * 32];   // 4 sub-tiles
  __shared__ alignas(16) short B3s[64 * 32];   // 4 sub-tiles

  int t = threadIdx.x;
  int lane = t & 63, wid = t >> 6;
  int lr = lane & 15;        // row within sub-tile
  int lk = (lane >> 4) * 8;  // k-chunk offset (elements)

  const short* xs = (const short*)xbf;
  const short* b1p = (const short*)w1t + (size_t)e * FDIM * CDIM;
  const short* b3p = (const short*)w3t + (size_t)e * FDIM * CDIM;

  // staging: wave w stages A sub-tiles 2w,2w+1 and B1/B3 sub-tile w
  int r0a = m0 + (2 * wid) * 16 + lr;
  int r1a = m0 + (2 * wid + 1) * 16 + lr;
  int t0 = lists[base + ((r0a < n_e) ? r0a : (n_e - 1))] >> 1;
  int t1 = lists[base + ((r1a < n_e) ? r1a : (n_e - 1))] >> 1;
  const short* aptr0 = xs + (size_t)t0 * CDIM + lk;
  const short* aptr1 = xs + (size_t)t1 * CDIM + lk;
  const short* bptr1 = b1p + (size_t)(f0 + wid * 16 + lr) * CDIM + lk;
  const short* bptr3 = b3p + (size_t)(f0 + wid * 16 + lr) * CDIM + lk;
  short* ldsA0 = &As[(2 * wid) * 512];
  short* ldsA1 = &As[(2 * wid + 1) * 512];
  short* ldsB1 = &B1s[wid * 512];
  short* ldsB3 = &B3s[wid * 512];

  f32x4 zero = {0.f, 0.f, 0.f, 0.f};
  f32x4 accg[4][2], accu[4][2];
#pragma unroll
  for (int i = 0; i < 4; i++)
#pragma unroll
    for (int j = 0; j < 2; j++) { accg[i][j] = zero; accu[i][j] = zero; }

  int asub = (wid & 1) * 4;   // A sub-tiles this wave consumes
  int bsub = (wid >> 1) * 2;  // B sub-tiles this wave consumes

  for (int kk = 0; kk < CDIM; kk += 32) {
    __syncthreads();
    g2l16(aptr0 + kk, ldsA0);
    g2l16(aptr1 + kk, ldsA1);
    g2l16(bptr1 + kk, ldsB1);
    g2l16(bptr3 + kk, ldsB3);
    __syncthreads();  // compiler emits vmcnt(0) drain before s_barrier
    bf16x8 af[4], b1f[2], b3f[2];
#pragma unroll
    for (int i = 0; i < 4; i++)
      af[i] = *(const bf16x8*)&As[(asub + i) * 512 + lane * 8];
#pragma unroll
    for (int j = 0; j < 2; j++) {
      b1f[j] = *(const bf16x8*)&B1s[(bsub + j) * 512 + lane * 8];
      b3f[j] = *(const bf16x8*)&B3s[(bsub + j) * 512 + lane * 8];
    }
#pragma unroll
    for (int i = 0; i < 4; i++)
#pragma unroll
      for (int j = 0; j < 2; j++) {
        accg[i][j] = __builtin_amdgcn_mfma_f32_16x16x32_bf16(af[i], b1f[j], accg[i][j], 0, 0, 0);
        accu[i][j] = __builtin_amdgcn_mfma_f32_16x16x32_bf16(af[i], b3f[j], accu[i][j], 0, 0, 0);
      }
  }

  int wm = (wid & 1) * 64, wf = (wid >> 1) * 32;
  int col = lane & 15;
  int rbase = (lane >> 4) * 4;
#pragma unroll
  for (int i = 0; i < 4; i++) {
#pragma unroll
    for (int r = 0; r < 4; r++) {
      int m = m0 + wm + i * 16 + rbase + r;
      if (m < n_e) {
        size_t hrow = (size_t)(base + m) * FDIM;
#pragma unroll
        for (int j = 0; j < 2; j++) {
          int f = f0 + wf + j * 16 + col;
          float g = accg[i][j][r];
          float u = accu[i][j][r];
          float sg = g / (1.f + __expf(-g));
          h[hrow + f] = __float2bfloat16(sg * u);
        }
      }
    }
  }
}

// ---------------- GEMM2: out[tok] += prob * (h @ w2) ----------------
__global__ __launch_bounds__(256) void gemm2_kernel(
    const __hip_bfloat16* __restrict__ h, const __hip_bfloat16* __restrict__ w2t,
    const int* __restrict__ counts, const int* __restrict__ bases,
    const int* __restrict__ lists, const float* __restrict__ pair_prob,
    float* __restrict__ out) {
  int e = blockIdx.z;
  int n_e = counts[e];
  int m0 = blockIdx.y * 128;
  if (m0 >= n_e) return;
  int base = bases[e];
  int c0 = blockIdx.x * 128;

  __shared__ alignas(16) short As[128 * 32];  // 8 sub-tiles
  __shared__ alignas(16) short Bs[128 * 32];  // 8 sub-tiles

  int t = threadIdx.x;
  int lane = t & 63, wid = t >> 6;
  int lr = lane & 15;
  int lk = (lane >> 4) * 8;

  const short* hp = (const short*)h;
  const short* bp = (const short*)w2t + (size_t)e * CDIM * FDIM;

  // staging: wave w stages A subs 2w,2w+1 and B subs 2w,2w+1
  int hr0 = base + m0 + (2 * wid) * 16 + lr;
  int hr1 = base + m0 + (2 * wid + 1) * 16 + lr;
  if (hr0 > 2 * N_TOK - 1) hr0 = 2 * N_TOK - 1;
  if (hr1 > 2 * N_TOK - 1) hr1 = 2 * N_TOK - 1;
  const short* aptr0 = hp + (size_t)hr0 * FDIM + lk;
  const short* aptr1 = hp + (size_t)hr1 * FDIM + lk;
  const short* bptr0 = bp + (size_t)(c0 + (2 * wid) * 16 + lr) * FDIM + lk;
  const short* bptr1 = bp + (size_t)(c0 + (2 * wid + 1) * 16 + lr) * FDIM + lk;
  short* ldsA0 = &As[(2 * wid) * 512];
  short* ldsA1 = &As[(2 * wid + 1) * 512];
  short* ldsB0 = &Bs[(2 * wid) * 512];
  short* ldsB1 = &Bs[(2 * wid + 1) * 512];

  f32x4 zero = {0.f, 0.f, 0.f, 0.f};
  f32x4 acc[4][4];
#pragma unroll
  for (int i = 0; i < 4; i++)
#pragma unroll
    for (int j = 0; j < 4; j++) acc[i][j] = zero;

  int asub = (wid & 1) * 4;
  int bsub = (wid >> 1) * 4;

  for (int kk = 0; kk < FDIM; kk += 32) {
    __syncthreads();
    g2l16(aptr0 + kk, ldsA0);
    g2l16(aptr1 + kk, ldsA1);
    g2l16(bptr0 + kk, ldsB0);
    g2l16(bptr1 + kk, ldsB1);
    __syncthreads();
    bf16x8 af[4], bfr[4];
#pragma unroll
    for (int i = 0; i < 4; i++)
      af[i] = *(const bf16x8*)&As[(asub + i) * 512 + lane * 8];
#pragma unroll
    for (int j = 0; j < 4; j++)
      bfr[j] = *(const bf16x8*)&Bs[(bsub + j) * 512 + lane * 8];
#pragma unroll
    for (int i = 0; i < 4; i++)
#pragma unroll
      for (int j = 0; j < 4; j++)
        acc[i][j] = __builtin_amdgcn_mfma_f32_16x16x32_bf16(af[i], bfr[j], acc[i][j], 0, 0, 0);
  }

  int wm = (wid & 1) * 64, wn = (wid >> 1) * 64;
  int col = lane & 15;
  int rbase = (lane >> 4) * 4;
#pragma unroll
  for (int i = 0; i < 4; i++) {
#pragma unroll
    for (int r = 0; r < 4; r++) {
      int m = m0 + wm + i * 16 + rbase + r;
      if (m < n_e) {
        int pr = lists[base + m];
        int tok = pr >> 1;
        float p = pair_prob[pr];
        size_t orow = (size_t)tok * CDIM;
#pragma unroll
        for (int j = 0; j < 4; j++) {
          int c = c0 + wn + j * 16 + col;
          atomicAdd(&out[orow + c], acc[i][j][r] * p);
        }
      }
    }
  }
}

extern "C" void kernel_launch(void* const* d_in, const int* in_sizes, int n_in,
                              void* d_out, int out_size, void* d_ws, size_t ws_size,
                              hipStream_t stream) {
  const float* x  = (const float*)d_in[0];
  const float* wr = (const float*)d_in[1];
  const float* w1 = (const float*)d_in[2];
  const float* w3 = (const float*)d_in[3];
  const float* w2 = (const float*)d_in[4];
  float* out = (float*)d_out;

  char* ws = (char*)d_ws;
  __hip_bfloat16* x_bf = (__hip_bfloat16*)(ws);                 // 16 MB
  __hip_bfloat16* h    = (__hip_bfloat16*)(ws + 16777216);      // 16 MB
  __hip_bfloat16* w1t  = (__hip_bfloat16*)(ws + 33554432);      // 32 MB
  __hip_bfloat16* w3t  = (__hip_bfloat16*)(ws + 67108864);      // 32 MB
  __hip_bfloat16* w2t  = (__hip_bfloat16*)(ws + 100663296);     // 32 MB
  int* counts  = (int*)(ws + 134217728);
  int* bases   = counts + 8;
  int* cursors = counts + 16;
  int* pair_expert = (int*)(ws + 134217728 + 128);
  float* pair_prob = (float*)(ws + 134217728 + 128 + 32768);
  int* lists       = (int*)(ws + 134217728 + 128 + 65536);

  hipMemsetAsync(d_out, 0, (size_t)N_TOK * CDIM * sizeof(float), stream);
  hipMemsetAsync(counts, 0, 128, stream);

  // w1,w3: [E][C][F] -> [E][F][C] bf16 ; w2: [E][F][C] -> [E][C][F] bf16
  transpose_to_bf16<<<dim3(FDIM / 32, CDIM / 64, EXP), 256, 0, stream>>>(w1, w1t, CDIM, FDIM);
  transpose_to_bf16<<<dim3(FDIM / 32, CDIM / 64, EXP), 256, 0, stream>>>(w3, w3t, CDIM, FDIM);
  transpose_to_bf16<<<dim3(CDIM / 32, FDIM / 64, EXP), 256, 0, stream>>>(w2, w2t, FDIM, CDIM);

  router_kernel<<<N_TOK, 256, 0, stream>>>(x, wr, x_bf, counts, pair_expert, pair_prob);
  scan_kernel<<<1, 64, 0, stream>>>(counts, bases);
  scatter_kernel<<<N_TOK / 256, 256, 0, stream>>>(pair_expert, bases, cursors, lists);

  gemm1_kernel<<<dim3(FDIM / 64, N_TOK / 128, EXP), 256, 0, stream>>>(
      x_bf, w1t, w3t, counts, bases, lists, h);
  gemm2_kernel<<<dim3(CDIM / 128, N_TOK / 128, EXP), 256, 0, stream>>>(
      h, w2t, counts, bases, lists, pair_prob, out);
}

// Round 3
// 625.800 us; speedup vs baseline: 1.1004x; 1.1004x over previous
//
#include <hip/hip_runtime.h>
#include <hip/hip_bf16.h>
#include <stdint.h>

#define N_TOK 4096
#define CDIM 2048
#define EXP 8
#define FDIM 1024
#define LDSTRIDE 40  // 80B rows: 16B-aligned b128 frags; conflicts measured benign (m98-class)

typedef __attribute__((ext_vector_type(4))) float f32x4;
typedef __attribute__((ext_vector_type(8))) short bf16x8;

// ---------------- transpose + fp32->bf16: in [E][R][Cc] -> out [E][Cc][R] ----------------
// 64x64 tile; coalesced 256B-per-row float4 reads; LDS float[64][65] (2-way free both phases);
// coalesced 32B-per-thread int4 bf16 writes.
__global__ __launch_bounds__(256) void transpose_to_bf16(
    const float* __restrict__ in, __hip_bfloat16* __restrict__ out, int R, int Cc) {
  __shared__ float tile[64][65];
  int e = blockIdx.z;
  const float* ip = in + (size_t)e * R * Cc;
  __hip_bfloat16* op = out + (size_t)e * R * Cc;
  int r0 = blockIdx.y * 64, c0 = blockIdx.x * 64;
  int t = threadIdx.x;
  {
    int r = t >> 2, cb = (t & 3) * 16;
    const float* src = ip + (size_t)(r0 + r) * Cc + c0 + cb;
#pragma unroll
    for (int i = 0; i < 4; i++) {
      float4 v = *(const float4*)(src + i * 4);
      tile[cb + i * 4 + 0][r] = v.x;
      tile[cb + i * 4 + 1][r] = v.y;
      tile[cb + i * 4 + 2][r] = v.z;
      tile[cb + i * 4 + 3][r] = v.w;
    }
  }
  __syncthreads();
  {
    int c = t >> 2, sb = (t & 3) * 16;
    union { int4 v[2]; __hip_bfloat16 h[16]; } u;
#pragma unroll
    for (int j = 0; j < 16; j++) u.h[j] = __float2bfloat16(tile[c][sb + j]);
    __hip_bfloat16* dst = op + (size_t)(c0 + c) * R + r0 + sb;
    *(int4*)(dst) = u.v[0];
    *(int4*)(dst + 8) = u.v[1];
  }
}

// ---------------- fp32 router + x->bf16 ----------------
__global__ __launch_bounds__(256) void router_kernel(
    const float* __restrict__ x, const float* __restrict__ wr,
    __hip_bfloat16* __restrict__ x_bf, int* __restrict__ counts,
    int* __restrict__ pair_expert, float* __restrict__ pair_prob) {
  int tok = blockIdx.x;
  const float* xr = x + (size_t)tok * CDIM;
  int t = threadIdx.x;
  float acc[EXP];
#pragma unroll
  for (int e = 0; e < EXP; e++) acc[e] = 0.f;
#pragma unroll
  for (int j = 0; j < 8; j++) {
    int c = j * 256 + t;
    float xv = xr[c];
    x_bf[(size_t)tok * CDIM + c] = __float2bfloat16(xv);
    const float4* wr4 = (const float4*)(wr + (size_t)c * EXP);
    float4 wa = wr4[0], wb = wr4[1];
    acc[0] += xv * wa.x; acc[1] += xv * wa.y; acc[2] += xv * wa.z; acc[3] += xv * wa.w;
    acc[4] += xv * wb.x; acc[5] += xv * wb.y; acc[6] += xv * wb.z; acc[7] += xv * wb.w;
  }
#pragma unroll
  for (int e = 0; e < EXP; e++) {
#pragma unroll
    for (int off = 32; off > 0; off >>= 1) acc[e] += __shfl_down(acc[e], off, 64);
  }
  __shared__ float wsum[4][EXP];
  int wid = t >> 6, lane = t & 63;
  if (lane == 0) {
#pragma unroll
    for (int e = 0; e < EXP; e++) wsum[wid][e] = acc[e];
  }
  __syncthreads();
  if (t == 0) {
    float lg[EXP];
#pragma unroll
    for (int e = 0; e < EXP; e++) lg[e] = wsum[0][e] + wsum[1][e] + wsum[2][e] + wsum[3][e];
    int i0 = 0;
#pragma unroll
    for (int e = 1; e < EXP; e++) if (lg[e] > lg[i0]) i0 = e;
    int i1 = (i0 == 0) ? 1 : 0;
#pragma unroll
    for (int e = 0; e < EXP; e++) if (e != i0 && lg[e] > lg[i1]) i1 = e;
    float e1 = __expf(lg[i1] - lg[i0]);
    float p0 = 1.f / (1.f + e1);
    pair_expert[tok * 2 + 0] = i0;
    pair_expert[tok * 2 + 1] = i1;
    pair_prob[tok * 2 + 0] = p0;
    pair_prob[tok * 2 + 1] = e1 * p0;
    atomicAdd(&counts[i0], 1);
    atomicAdd(&counts[i1], 1);
  }
}

// ---------------- tiny exclusive scan over 8 counts ----------------
__global__ void scan_kernel(const int* __restrict__ counts, int* __restrict__ bases) {
  if (threadIdx.x == 0) {
    int s = 0;
    for (int e = 0; e < EXP; e++) { bases[e] = s; s += counts[e]; }
  }
}

// ---------------- scatter pairs into per-expert lists ----------------
__global__ __launch_bounds__(256) void scatter_kernel(
    const int* __restrict__ pair_expert, const int* __restrict__ bases,
    int* __restrict__ cursors, int* __restrict__ lists) {
  int tok = blockIdx.x * 256 + threadIdx.x;
  if (tok >= N_TOK) return;
#pragma unroll
  for (int k = 0; k < 2; k++) {
    int e = pair_expert[tok * 2 + k];
    int pos = atomicAdd(&cursors[e], 1);
    lists[bases[e] + pos] = tok * 2 + k;
  }
}

// ---------------- GEMM1: h = silu(x@w1) * (x@w3); explicit VGPR prefetch pipeline ----------------
__global__ __launch_bounds__(256) void gemm1_kernel(
    const __hip_bfloat16* __restrict__ xbf, const __hip_bfloat16* __restrict__ w1t,
    const __hip_bfloat16* __restrict__ w3t, const int* __restrict__ counts,
    const int* __restrict__ bases, const int* __restrict__ lists,
    __hip_bfloat16* __restrict__ h) {
  int e = blockIdx.z;
  int n_e = counts[e];
  int m0 = blockIdx.y * 128;
  if (m0 >= n_e) return;
  int base = bases[e];
  int f0 = blockIdx.x * 64;

  __shared__ short As[128 * LDSTRIDE];
  __shared__ short B1s[64 * LDSTRIDE];
  __shared__ short B3s[64 * LDSTRIDE];

  int t = threadIdx.x;
  int lane = t & 63, wid = t >> 6;

  int arow = t >> 1;
  int achunk = (t & 1) * 16;  // shorts
  int rr = m0 + arow;
  int pair = lists[base + ((rr < n_e) ? rr : 0)];
  int tokA = pair >> 1;

  const short* xs = (const short*)xbf;
  const short* b1p = (const short*)w1t + (size_t)e * FDIM * CDIM;
  const short* b3p = (const short*)w3t + (size_t)e * FDIM * CDIM;
  int brow = (t & 127) >> 1;
  bool doB1 = (t < 128);
  const short* bsrc = (doB1 ? b1p : b3p) + (size_t)(f0 + brow) * CDIM + achunk;
  short* bdst = (doB1 ? B1s : B3s) + brow * LDSTRIDE + achunk;
  const short* asrc = xs + (size_t)tokA * CDIM + achunk;
  short* adst = As + arow * LDSTRIDE + achunk;

  // prologue: prefetch tile 0 into registers
  int4 pa0 = *(const int4*)(asrc);
  int4 pa1 = *(const int4*)(asrc + 8);
  int4 pb0 = *(const int4*)(bsrc);
  int4 pb1 = *(const int4*)(bsrc + 8);

  f32x4 zero = {0.f, 0.f, 0.f, 0.f};
  f32x4 accg[4][2], accu[4][2];
#pragma unroll
  for (int i = 0; i < 4; i++)
#pragma unroll
    for (int j = 0; j < 2; j++) { accg[i][j] = zero; accu[i][j] = zero; }

  int wm = (wid & 1) * 64, wf = (wid >> 1) * 32;
  int kq = (lane >> 4) * 8;
  int rsel = lane & 15;

  for (int kk = 0; kk < CDIM; kk += 32) {
    __syncthreads();
    *(int4*)(adst) = pa0;
    *(int4*)(adst + 8) = pa1;
    *(int4*)(bdst) = pb0;
    *(int4*)(bdst + 8) = pb1;
    __syncthreads();
    if (kk + 32 < CDIM) {  // issue next tile's loads; they overlap the MFMAs below
      pa0 = *(const int4*)(asrc + kk + 32);
      pa1 = *(const int4*)(asrc + kk + 40);
      pb0 = *(const int4*)(bsrc + kk + 32);
      pb1 = *(const int4*)(bsrc + kk + 40);
    }
    bf16x8 af[4], b1f[2], b3f[2];
#pragma unroll
    for (int i = 0; i < 4; i++)
      af[i] = *(const bf16x8*)(As + (wm + i * 16 + rsel) * LDSTRIDE + kq);
#pragma unroll
    for (int j = 0; j < 2; j++) {
      b1f[j] = *(const bf16x8*)(B1s + (wf + j * 16 + rsel) * LDSTRIDE + kq);
      b3f[j] = *(const bf16x8*)(B3s + (wf + j * 16 + rsel) * LDSTRIDE + kq);
    }
#pragma unroll
    for (int i = 0; i < 4; i++)
#pragma unroll
      for (int j = 0; j < 2; j++) {
        accg[i][j] = __builtin_amdgcn_mfma_f32_16x16x32_bf16(af[i], b1f[j], accg[i][j], 0, 0, 0);
        accu[i][j] = __builtin_amdgcn_mfma_f32_16x16x32_bf16(af[i], b3f[j], accu[i][j], 0, 0, 0);
      }
  }

  int col = lane & 15;
  int rbase = (lane >> 4) * 4;
#pragma unroll
  for (int i = 0; i < 4; i++) {
#pragma unroll
    for (int r = 0; r < 4; r++) {
      int m = m0 + wm + i * 16 + rbase + r;
      if (m < n_e) {
        size_t hrow = (size_t)(base + m) * FDIM;
#pragma unroll
        for (int j = 0; j < 2; j++) {
          int f = f0 + wf + j * 16 + col;
          float g = accg[i][j][r];
          float u = accu[i][j][r];
          float sg = g / (1.f + __expf(-g));
          h[hrow + f] = __float2bfloat16(sg * u);
        }
      }
    }
  }
}

// ---------------- GEMM2: out[tok] += prob * (h @ w2); explicit VGPR prefetch pipeline ----------------
__global__ __launch_bounds__(256) void gemm2_kernel(
    const __hip_bfloat16* __restrict__ h, const __hip_bfloat16* __restrict__ w2t,
    const int* __restrict__ counts, const int* __restrict__ bases,
    const int* __restrict__ lists, const float* __restrict__ pair_prob,
    float* __restrict__ out) {
  int e = blockIdx.z;
  int n_e = counts[e];
  int m0 = blockIdx.y * 128;
  if (m0 >= n_e) return;
  int base = bases[e];
  int c0 = blockIdx.x * 128;

  __shared__ short As[128 * LDSTRIDE];
  __shared__ short Bs[128 * LDSTRIDE];

  int t = threadIdx.x;
  int lane = t & 63, wid = t >> 6;

  int arow = t >> 1;
  int achunk = (t & 1) * 16;
  int hr = base + m0 + arow;
  if (hr > 2 * N_TOK - 1) hr = 2 * N_TOK - 1;
  const short* hp = (const short*)h;
  const short* bp = (const short*)w2t + (size_t)e * CDIM * FDIM;
  const short* asrc = hp + (size_t)hr * FDIM + achunk;
  const short* bsrc = bp + (size_t)(c0 + arow) * FDIM + achunk;
  short* adst = As + arow * LDSTRIDE + achunk;
  short* bdst = Bs + arow * LDSTRIDE + achunk;

  int4 pa0 = *(const int4*)(asrc);
  int4 pa1 = *(const int4*)(asrc + 8);
  int4 pb0 = *(const int4*)(bsrc);
  int4 pb1 = *(const int4*)(bsrc + 8);

  f32x4 zero = {0.f, 0.f, 0.f, 0.f};
  f32x4 acc[4][4];
#pragma unroll
  for (int i = 0; i < 4; i++)
#pragma unroll
    for (int j = 0; j < 4; j++) acc[i][j] = zero;

  int wm = (wid & 1) * 64, wn = (wid >> 1) * 64;
  int kq = (lane >> 4) * 8;
  int rsel = lane & 15;

  for (int kk = 0; kk < FDIM; kk += 32) {
    __syncthreads();
    *(int4*)(adst) = pa0;
    *(int4*)(adst + 8) = pa1;
    *(int4*)(bdst) = pb0;
    *(int4*)(bdst + 8) = pb1;
    __syncthreads();
    if (kk + 32 < FDIM) {
      pa0 = *(const int4*)(asrc + kk + 32);
      pa1 = *(const int4*)(asrc + kk + 40);
      pb0 = *(const int4*)(bsrc + kk + 32);
      pb1 = *(const int4*)(bsrc + kk + 40);
    }
    bf16x8 af[4], bfr[4];
#pragma unroll
    for (int i = 0; i < 4; i++)
      af[i] = *(const bf16x8*)(As + (wm + i * 16 + rsel) * LDSTRIDE + kq);
#pragma unroll
    for (int j = 0; j < 4; j++)
      bfr[j] = *(const bf16x8*)(Bs + (wn + j * 16 + rsel) * LDSTRIDE + kq);
#pragma unroll
    for (int i = 0; i < 4; i++)
#pragma unroll
      for (int j = 0; j < 4; j++)
        acc[i][j] = __builtin_amdgcn_mfma_f32_16x16x32_bf16(af[i], bfr[j], acc[i][j], 0, 0, 0);
  }

  int col = lane & 15;
  int rbase = (lane >> 4) * 4;
#pragma unroll
  for (int i = 0; i < 4; i++) {
#pragma unroll
    for (int r = 0; r < 4; r++) {
      int m = m0 + wm + i * 16 + rbase + r;
      if (m < n_e) {
        int pr = lists[base + m];
        int tok = pr >> 1;
        float p = pair_prob[pr];
        size_t orow = (size_t)tok * CDIM;
#pragma unroll
        for (int j = 0; j < 4; j++) {
          int c = c0 + wn + j * 16 + col;
          atomicAdd(&out[orow + c], acc[i][j][r] * p);
        }
      }
    }
  }
}

extern "C" void kernel_launch(void* const* d_in, const int* in_sizes, int n_in,
                              void* d_out, int out_size, void* d_ws, size_t ws_size,
                              hipStream_t stream) {
  const float* x  = (const float*)d_in[0];
  const float* wr = (const float*)d_in[1];
  const float* w1 = (const float*)d_in[2];
  const float* w3 = (const float*)d_in[3];
  const float* w2 = (const float*)d_in[4];
  float* out = (float*)d_out;

  char* ws = (char*)d_ws;
  __hip_bfloat16* x_bf = (__hip_bfloat16*)(ws);                 // 16 MB
  __hip_bfloat16* h    = (__hip_bfloat16*)(ws + 16777216);      // 16 MB
  __hip_bfloat16* w1t  = (__hip_bfloat16*)(ws + 33554432);      // 32 MB
  __hip_bfloat16* w3t  = (__hip_bfloat16*)(ws + 67108864);      // 32 MB
  __hip_bfloat16* w2t  = (__hip_bfloat16*)(ws + 100663296);     // 32 MB
  int* counts  = (int*)(ws + 134217728);
  int* bases   = counts + 8;
  int* cursors = counts + 16;
  int* pair_expert = (int*)(ws + 134217728 + 128);
  float* pair_prob = (float*)(ws + 134217728 + 128 + 32768);
  int* lists       = (int*)(ws + 134217728 + 128 + 65536);

  hipMemsetAsync(d_out, 0, (size_t)N_TOK * CDIM * sizeof(float), stream);
  hipMemsetAsync(counts, 0, 128, stream);

  // w1,w3: [E][C][F] -> [E][F][C] bf16 ; w2: [E][F][C] -> [E][C][F] bf16
  transpose_to_bf16<<<dim3(FDIM / 64, CDIM / 64, EXP), 256, 0, stream>>>(w1, w1t, CDIM, FDIM);
  transpose_to_bf16<<<dim3(FDIM / 64, CDIM / 64, EXP), 256, 0, stream>>>(w3, w3t, CDIM, FDIM);
  transpose_to_bf16<<<dim3(CDIM / 64, FDIM / 64, EXP), 256, 0, stream>>>(w2, w2t, FDIM, CDIM);

  router_kernel<<<N_TOK, 256, 0, stream>>>(x, wr, x_bf, counts, pair_expert, pair_prob);
  scan_kernel<<<1, 64, 0, stream>>>(counts, bases);
  scatter_kernel<<<N_TOK / 256, 256, 0, stream>>>(pair_expert, bases, cursors, lists);

  gemm1_kernel<<<dim3(FDIM / 64, N_TOK / 128, EXP), 256, 0, stream>>>(
      x_bf, w1t, w3t, counts, bases, lists, h);
  gemm2_kernel<<<dim3(CDIM / 128, N_TOK / 128, EXP), 256, 0, stream>>>(
      h, w2t, counts, bases, lists, pair_prob, out);
}